// Round 1
// baseline (201.776 us; speedup 1.0000x reference)
//
#include <hip/hip_runtime.h>

// Problem constants (from reference): B=128 targets, D=384, DO=2048, K=10.
#define DIM   384
#define DIMO  2048
#define KNN   10

// -------------------------------------------------------------------------
// Kernel 1: scores[m][n] = ||data_n||^2 - 2 * dot(target_m, data_n)
// (monotone-equivalent to reference distance for per-row top-k ordering)
// Tile: BM=128 (all targets) x BN=128 data cols, BK=32, 256 threads,
// 8x8 micro-tile per thread split into 4 quadrants (conflict-free b128 reads).
// -------------------------------------------------------------------------
__global__ __launch_bounds__(256) void score_kernel(
    const float* __restrict__ tgt,     // [128][384]
    const float* __restrict__ dat,     // [N][384]
    float* __restrict__ scores,        // [128][N]
    int N)
{
    __shared__ float sA[32][128];      // targets^T tile: [k][m]
    __shared__ float sB[32][128];      // data^T tile:    [k][n_local]
    __shared__ float d2p[128][8];      // d^2 partials
    __shared__ float d2s[128];         // d^2 per local data row

    const int tid   = threadIdx.x;
    const int nbase = blockIdx.x * 128;

    const int lrow  = tid >> 3;        // 0..31 (staging row)
    const int lcol4 = (tid & 7) << 2;  // 0,4,...,28 (staging col, float4)

    const int tm = tid >> 4;           // 0..15 -> rows tm*4+i and 64+tm*4+i
    const int tn = tid & 15;           // 0..15 -> cols tn*4+j and 64+tn*4+j

    float acc[8][8];
#pragma unroll
    for (int i = 0; i < 8; ++i)
#pragma unroll
        for (int j = 0; j < 8; ++j) acc[i][j] = 0.f;

    float d2acc[4] = {0.f, 0.f, 0.f, 0.f};

    for (int k0 = 0; k0 < DIM; k0 += 32) {
        __syncthreads();
        // stage targets tile (transposed)
#pragma unroll
        for (int it = 0; it < 4; ++it) {
            int row = lrow + it * 32;
            float4 v = *reinterpret_cast<const float4*>(&tgt[row * DIM + k0 + lcol4]);
            sA[lcol4 + 0][row] = v.x;
            sA[lcol4 + 1][row] = v.y;
            sA[lcol4 + 2][row] = v.z;
            sA[lcol4 + 3][row] = v.w;
        }
        // stage data tile (transposed) + accumulate ||d||^2
#pragma unroll
        for (int it = 0; it < 4; ++it) {
            int row = lrow + it * 32;
            int g   = nbase + row;
            float4 v = make_float4(0.f, 0.f, 0.f, 0.f);
            if (g < N)
                v = *reinterpret_cast<const float4*>(&dat[(size_t)g * DIM + k0 + lcol4]);
            sB[lcol4 + 0][row] = v.x;
            sB[lcol4 + 1][row] = v.y;
            sB[lcol4 + 2][row] = v.z;
            sB[lcol4 + 3][row] = v.w;
            d2acc[it] += v.x * v.x + v.y * v.y + v.z * v.z + v.w * v.w;
        }
        __syncthreads();
#pragma unroll
        for (int kk = 0; kk < 32; ++kk) {
            float a[8], b[8];
            *reinterpret_cast<float4*>(&a[0]) = *reinterpret_cast<const float4*>(&sA[kk][tm * 4]);
            *reinterpret_cast<float4*>(&a[4]) = *reinterpret_cast<const float4*>(&sA[kk][64 + tm * 4]);
            *reinterpret_cast<float4*>(&b[0]) = *reinterpret_cast<const float4*>(&sB[kk][tn * 4]);
            *reinterpret_cast<float4*>(&b[4]) = *reinterpret_cast<const float4*>(&sB[kk][64 + tn * 4]);
#pragma unroll
            for (int i = 0; i < 8; ++i)
#pragma unroll
                for (int j = 0; j < 8; ++j)
                    acc[i][j] = fmaf(a[i], b[j], acc[i][j]);
        }
    }

    // reduce ||d||^2 partials (8 staging threads per row)
#pragma unroll
    for (int it = 0; it < 4; ++it)
        d2p[lrow + it * 32][tid & 7] = d2acc[it];
    __syncthreads();
    if (tid < 128) {
        float s = 0.f;
#pragma unroll
        for (int j = 0; j < 8; ++j) s += d2p[tid][j];
        d2s[tid] = s;
    }
    __syncthreads();

    // epilogue: score = d2 - 2*dot, coalesced float4 stores
#pragma unroll
    for (int qi = 0; qi < 2; ++qi)
#pragma unroll
        for (int i = 0; i < 4; ++i) {
            int m = qi * 64 + tm * 4 + i;
#pragma unroll
            for (int qj = 0; qj < 2; ++qj) {
                int nl = qj * 64 + tn * 4;
                int n  = nbase + nl;
                if (n >= N) continue;
                float4 s;
                s.x = d2s[nl + 0] - 2.f * acc[qi * 4 + i][qj * 4 + 0];
                s.y = d2s[nl + 1] - 2.f * acc[qi * 4 + i][qj * 4 + 1];
                s.z = d2s[nl + 2] - 2.f * acc[qi * 4 + i][qj * 4 + 2];
                s.w = d2s[nl + 3] - 2.f * acc[qi * 4 + i][qj * 4 + 3];
                if (n + 3 < N) {
                    *reinterpret_cast<float4*>(&scores[(size_t)m * N + n]) = s;
                } else {
                    float tmp[4] = {s.x, s.y, s.z, s.w};
                    for (int j = 0; j < 4 && n + j < N; ++j)
                        scores[(size_t)m * N + n + j] = tmp[j];
                }
            }
        }
}

// -------------------------------------------------------------------------
// Kernel 2: per target row, select 10 smallest scores (ascending, ties ->
// lower index, matching jax.lax.top_k stability) and gather OTinput/OToutput.
// One block per row; per-thread register top-10 (static indexing only),
// then heads-merge via LDS argmin reduction, then cooperative gather.
// -------------------------------------------------------------------------
__global__ __launch_bounds__(256) void topk_gather_kernel(
    const float* __restrict__ scores,  // [B][N]
    const float* __restrict__ OTin,    // [N][384]
    const float* __restrict__ OTout,   // [N][2048]
    float* __restrict__ out,           // [B*10*384] ++ [B*10*2048]
    int N, int B)
{
    const int b   = blockIdx.x;
    const int tid = threadIdx.x;
    const float* row = scores + (size_t)b * N;

    // per-thread sorted top-10 (ascending) — all accesses compile-time indexed
    float ts[KNN];
    int   ti[KNN];
#pragma unroll
    for (int k = 0; k < KNN; ++k) { ts[k] = 3.402823466e38f; ti[k] = 0x7fffffff; }

    for (int n = tid; n < N; n += 256) {
        float s = row[n];
        if (s < ts[KNN - 1]) {   // strict: equal keeps earlier (lower) index
            ts[KNN - 1] = s;
            ti[KNN - 1] = n;
            // bubble new element toward front (strict compare keeps stability)
#pragma unroll
            for (int p = KNN - 1; p > 0; --p) {
                if (ts[p] < ts[p - 1]) {
                    float fs = ts[p]; ts[p] = ts[p - 1]; ts[p - 1] = fs;
                    int   fi = ti[p]; ti[p] = ti[p - 1]; ti[p - 1] = fi;
                }
            }
        }
    }

    // dump sorted candidate lists to LDS for dynamic-index head access
    __shared__ float cs[256 * KNN];
    __shared__ int   ci[256 * KNN];
    __shared__ float rs[256];
    __shared__ int   ri[256];
    __shared__ int   rt[256];
    __shared__ int   sel[KNN];

#pragma unroll
    for (int k = 0; k < KNN; ++k) {
        cs[tid * KNN + k] = ts[k];
        ci[tid * KNN + k] = ti[k];
    }

    int ptr = 0;
    for (int k = 0; k < KNN; ++k) {
        rs[tid] = cs[tid * KNN + ptr];
        ri[tid] = ci[tid * KNN + ptr];
        rt[tid] = tid;
        __syncthreads();
        for (int off = 128; off > 0; off >>= 1) {
            if (tid < off) {
                float s2 = rs[tid + off]; int i2 = ri[tid + off];
                float s1 = rs[tid];       int i1 = ri[tid];
                if (s2 < s1 || (s2 == s1 && i2 < i1)) {
                    rs[tid] = s2; ri[tid] = i2; rt[tid] = rt[tid + off];
                }
            }
            __syncthreads();
        }
        if (tid == 0) sel[k] = ri[0];
        if (tid == rt[0]) ptr++;           // winner advances its head
        __syncthreads();
    }

    // gather: out0[b][k][0:384] and out1[b][k][0:2048], float4 coalesced
    const size_t o1 = (size_t)B * KNN * DIM;
    for (int q = tid; q < KNN * (DIM / 4); q += 256) {
        int k = q / (DIM / 4);
        int c = (q - k * (DIM / 4)) * 4;
        int idx = sel[k];
        *reinterpret_cast<float4*>(&out[((size_t)b * KNN + k) * DIM + c]) =
            *reinterpret_cast<const float4*>(&OTin[(size_t)idx * DIM + c]);
    }
    for (int q = tid; q < KNN * (DIMO / 4); q += 256) {
        int k = q / (DIMO / 4);
        int c = (q - k * (DIMO / 4)) * 4;
        int idx = sel[k];
        *reinterpret_cast<float4*>(&out[o1 + ((size_t)b * KNN + k) * DIMO + c]) =
            *reinterpret_cast<const float4*>(&OTout[(size_t)idx * DIMO + c]);
    }
}

extern "C" void kernel_launch(void* const* d_in, const int* in_sizes, int n_in,
                              void* d_out, int out_size, void* d_ws, size_t ws_size,
                              hipStream_t stream) {
    const float* targets = (const float*)d_in[0];
    const float* data    = (const float*)d_in[1];
    const float* OTin    = (const float*)d_in[2];
    const float* OTout   = (const float*)d_in[3];
    float* out = (float*)d_out;

    const int B = in_sizes[0] / DIM;   // 128
    const int N = in_sizes[1] / DIM;   // 50000

    float* scores = (float*)d_ws;      // B * N floats = 25.6 MB

    const int nblocks = (N + 127) / 128;
    score_kernel<<<nblocks, 256, 0, stream>>>(targets, data, scores, N);
    topk_gather_kernel<<<B, 256, 0, stream>>>(scores, OTin, OTout, out, N, B);
}

// Round 2
// 190.191 us; speedup vs baseline: 1.0609x; 1.0609x over previous
//
#include <hip/hip_runtime.h>

// Problem constants (from reference): B=128 targets, D=384, DO=2048, K=10.
#define DIM   384
#define DIMO  2048
#define KNN   10
#define FINF  3.0e38f

// -------------------------------------------------------------------------
// Kernel 1: fused score + per-block per-row top-10.
// score[m][n] = ||data_n||^2 - 2*dot(target_m, data_n)  (rank-equivalent to
// the reference distance). 128x128 tile GEMM (BM=128 targets, BN=128 data),
// BK=32, 256 threads, 8x8 micro-tile in 4 quadrants. Epilogue: stage scores
// into padded LDS [64][129] one half at a time, 1 thread/row insertion-sorts
// top-10 (ascending col order + strict < == stable lowest-index ties), and
// writes (score, idx) candidates: cand[row][blk*10+k].
// -------------------------------------------------------------------------
__global__ __launch_bounds__(256) void score_topk_kernel(
    const float* __restrict__ tgt,     // [128][384]
    const float* __restrict__ dat,     // [N][384]
    float* __restrict__ cand_s,        // [128][nblk*10]
    int*   __restrict__ cand_i,        // [128][nblk*10]
    int N, int nblk)
{
    // 33 KB raw LDS: GEMM phase uses sA[32][128] + sB[32][128]; epilogue
    // reuses the same bytes as sc[64][129] (pad => (row+col)%32 banks, conflict-free scan)
    __shared__ float smem[64 * 129];
    float (*sA)[128] = reinterpret_cast<float(*)[128]>(smem);
    float (*sB)[128] = reinterpret_cast<float(*)[128]>(smem + 32 * 128);
    float (*sc)[129] = reinterpret_cast<float(*)[129]>(smem);

    __shared__ float d2p[128][8];      // ||d||^2 partials
    __shared__ float d2s[128];         // ||d||^2 per local data col

    const int tid   = threadIdx.x;
    const int nbase = blockIdx.x * 128;

    const int lrow  = tid >> 3;        // 0..31 (staging row)
    const int lcol4 = (tid & 7) << 2;  // 0,4,...,28 (staging col, float4)

    const int tm = tid >> 4;           // 0..15
    const int tn = tid & 15;           // 0..15

    float acc[8][8];
#pragma unroll
    for (int i = 0; i < 8; ++i)
#pragma unroll
        for (int j = 0; j < 8; ++j) acc[i][j] = 0.f;

    float d2acc[4] = {0.f, 0.f, 0.f, 0.f};

    for (int k0 = 0; k0 < DIM; k0 += 32) {
        __syncthreads();
#pragma unroll
        for (int it = 0; it < 4; ++it) {
            int row = lrow + it * 32;
            float4 v = *reinterpret_cast<const float4*>(&tgt[row * DIM + k0 + lcol4]);
            sA[lcol4 + 0][row] = v.x;
            sA[lcol4 + 1][row] = v.y;
            sA[lcol4 + 2][row] = v.z;
            sA[lcol4 + 3][row] = v.w;
        }
#pragma unroll
        for (int it = 0; it < 4; ++it) {
            int row = lrow + it * 32;
            int g   = nbase + row;
            float4 v = make_float4(0.f, 0.f, 0.f, 0.f);
            if (g < N)
                v = *reinterpret_cast<const float4*>(&dat[(size_t)g * DIM + k0 + lcol4]);
            sB[lcol4 + 0][row] = v.x;
            sB[lcol4 + 1][row] = v.y;
            sB[lcol4 + 2][row] = v.z;
            sB[lcol4 + 3][row] = v.w;
            d2acc[it] += v.x * v.x + v.y * v.y + v.z * v.z + v.w * v.w;
        }
        __syncthreads();
#pragma unroll
        for (int kk = 0; kk < 32; ++kk) {
            float a[8], b[8];
            *reinterpret_cast<float4*>(&a[0]) = *reinterpret_cast<const float4*>(&sA[kk][tm * 4]);
            *reinterpret_cast<float4*>(&a[4]) = *reinterpret_cast<const float4*>(&sA[kk][64 + tm * 4]);
            *reinterpret_cast<float4*>(&b[0]) = *reinterpret_cast<const float4*>(&sB[kk][tn * 4]);
            *reinterpret_cast<float4*>(&b[4]) = *reinterpret_cast<const float4*>(&sB[kk][64 + tn * 4]);
#pragma unroll
            for (int i = 0; i < 8; ++i)
#pragma unroll
                for (int j = 0; j < 8; ++j)
                    acc[i][j] = fmaf(a[i], b[j], acc[i][j]);
        }
    }

    // reduce ||d||^2 partials
#pragma unroll
    for (int it = 0; it < 4; ++it)
        d2p[lrow + it * 32][tid & 7] = d2acc[it];
    __syncthreads();
    if (tid < 128) {
        float s = 0.f;
#pragma unroll
        for (int j = 0; j < 8; ++j) s += d2p[tid][j];
        d2s[tid] = s;
    }

    // epilogue: two 64-row halves; stage scores -> LDS, 1 thread/row top-10
    const int M = nblk * KNN;
    for (int h = 0; h < 2; ++h) {
        __syncthreads();   // prev phase (GEMM reads / prior-half scan) done
        // stage this half's scores: rows h*64 + (tm*4+i), cols qj*64+tn*4+j
#pragma unroll
        for (int i = 0; i < 4; ++i) {
            int l = tm * 4 + i;
#pragma unroll
            for (int qj = 0; qj < 2; ++qj)
#pragma unroll
                for (int j = 0; j < 4; ++j) {
                    int cl = qj * 64 + tn * 4 + j;
                    int n  = nbase + cl;
                    float s = (n < N) ? d2s[cl] - 2.f * acc[h * 4 + i][qj * 4 + j]
                                      : FINF;
                    sc[l][cl] = s;
                }
        }
        __syncthreads();
        if (tid < 64) {
            int grow = h * 64 + tid;
            float ts[KNN];
            int   ti[KNN];
#pragma unroll
            for (int k = 0; k < KNN; ++k) { ts[k] = FINF; ti[k] = 0x7fffffff; }
            for (int c = 0; c < 128; ++c) {
                float s = sc[tid][c];
                if (s < ts[KNN - 1]) {
                    ts[KNN - 1] = s;
                    ti[KNN - 1] = nbase + c;
#pragma unroll
                    for (int p = KNN - 1; p > 0; --p) {
                        if (ts[p] < ts[p - 1]) {
                            float fs = ts[p]; ts[p] = ts[p - 1]; ts[p - 1] = fs;
                            int   fi = ti[p]; ti[p] = ti[p - 1]; ti[p - 1] = fi;
                        }
                    }
                }
            }
            size_t base = (size_t)grow * M + (size_t)blockIdx.x * KNN;
#pragma unroll
            for (int k = 0; k < KNN; ++k) {
                cand_s[base + k] = ts[k];
                cand_i[base + k] = ti[k];
            }
        }
    }
}

// -------------------------------------------------------------------------
// Kernel 2: per target row, merge nblk*10 candidates -> global top-10
// (lexicographic (score, idx): ascending score, ties -> lower index, matching
// jax.lax.top_k stability). Emits selected indices only.
// -------------------------------------------------------------------------
__global__ __launch_bounds__(256) void select_kernel(
    const float* __restrict__ cand_s,  // [B][M]
    const int*   __restrict__ cand_i,  // [B][M]
    int* __restrict__ seldev,          // [B][10]
    int M)
{
    const int b   = blockIdx.x;
    const int tid = threadIdx.x;
    const float* rs_ = cand_s + (size_t)b * M;
    const int*   ri_ = cand_i + (size_t)b * M;

    float ts[KNN];
    int   ti[KNN];
#pragma unroll
    for (int k = 0; k < KNN; ++k) { ts[k] = FINF; ti[k] = 0x7fffffff; }

    for (int j = tid; j < M; j += 256) {
        float s = rs_[j];
        int   id = ri_[j];
        if (s < ts[KNN - 1] || (s == ts[KNN - 1] && id < ti[KNN - 1])) {
            ts[KNN - 1] = s;
            ti[KNN - 1] = id;
#pragma unroll
            for (int p = KNN - 1; p > 0; --p) {
                bool sw = (ts[p] < ts[p - 1]) ||
                          (ts[p] == ts[p - 1] && ti[p] < ti[p - 1]);
                if (sw) {
                    float fs = ts[p]; ts[p] = ts[p - 1]; ts[p - 1] = fs;
                    int   fi = ti[p]; ti[p] = ti[p - 1]; ti[p - 1] = fi;
                }
            }
        }
    }

    __shared__ float cs[256 * KNN];
    __shared__ int   ci[256 * KNN];
    __shared__ float rs[256];
    __shared__ int   ri[256];
    __shared__ int   rt[256];
    __shared__ int   sel[KNN];

#pragma unroll
    for (int k = 0; k < KNN; ++k) {
        cs[tid * KNN + k] = ts[k];
        ci[tid * KNN + k] = ti[k];
    }

    int ptr = 0;
    for (int k = 0; k < KNN; ++k) {
        rs[tid] = cs[tid * KNN + ptr];
        ri[tid] = ci[tid * KNN + ptr];
        rt[tid] = tid;
        __syncthreads();
        for (int off = 128; off > 0; off >>= 1) {
            if (tid < off) {
                float s2 = rs[tid + off]; int i2 = ri[tid + off];
                float s1 = rs[tid];       int i1 = ri[tid];
                if (s2 < s1 || (s2 == s1 && i2 < i1)) {
                    rs[tid] = s2; ri[tid] = i2; rt[tid] = rt[tid + off];
                }
            }
            __syncthreads();
        }
        if (tid == 0) sel[k] = ri[0];
        if (tid == rt[0]) ptr++;           // winner advances its head
        __syncthreads();
    }

    if (tid < KNN) seldev[b * KNN + tid] = sel[tid];
}

// -------------------------------------------------------------------------
// Kernel 3: gather. One block per (target, k) pair -> full-device occupancy.
// -------------------------------------------------------------------------
__global__ __launch_bounds__(256) void gather_kernel(
    const int* __restrict__ seldev,    // [B*10]
    const float* __restrict__ OTin,    // [N][384]
    const float* __restrict__ OTout,   // [N][2048]
    float* __restrict__ out,           // [B*10*384] ++ [B*10*2048]
    int B)
{
    const int bid = blockIdx.x;        // 0 .. B*KNN-1  (= b*KNN + k)
    const int tid = threadIdx.x;
    const int idx = seldev[bid];
    const size_t o1 = (size_t)B * KNN * DIM;

    const float4* in4  = reinterpret_cast<const float4*>(&OTin[(size_t)idx * DIM]);
    float4*       out4 = reinterpret_cast<float4*>(&out[(size_t)bid * DIM]);
    for (int q = tid; q < DIM / 4; q += 256) out4[q] = in4[q];

    const float4* ino4  = reinterpret_cast<const float4*>(&OTout[(size_t)idx * DIMO]);
    float4*       outo4 = reinterpret_cast<float4*>(&out[o1 + (size_t)bid * DIMO]);
    for (int q = tid; q < DIMO / 4; q += 256) outo4[q] = ino4[q];
}

extern "C" void kernel_launch(void* const* d_in, const int* in_sizes, int n_in,
                              void* d_out, int out_size, void* d_ws, size_t ws_size,
                              hipStream_t stream) {
    const float* targets = (const float*)d_in[0];
    const float* data    = (const float*)d_in[1];
    const float* OTin    = (const float*)d_in[2];
    const float* OTout   = (const float*)d_in[3];
    float* out = (float*)d_out;

    const int B = in_sizes[0] / DIM;   // 128
    const int N = in_sizes[1] / DIM;   // 50000

    const int nblk = (N + 127) / 128;  // 391
    const int M    = nblk * KNN;       // 3910

    float* cand_s = (float*)d_ws;                       // B*M floats (~2 MB)
    int*   cand_i = (int*)(cand_s + (size_t)B * M);     // B*M ints  (~2 MB)
    int*   seldev = (int*)(cand_i + (size_t)B * M);     // B*KNN ints

    score_topk_kernel<<<nblk, 256, 0, stream>>>(targets, data, cand_s, cand_i, N, nblk);
    select_kernel<<<B, 256, 0, stream>>>(cand_s, cand_i, seldev, M);
    gather_kernel<<<B * KNN, 256, 0, stream>>>(seldev, OTin, OTout, out, B);
}

// Round 3
// 147.159 us; speedup vs baseline: 1.3711x; 1.2924x over previous
//
#include <hip/hip_runtime.h>

// Problem constants: B=128 targets, N=50000 data, D=384, DO=2048, K=10.
#define DIM   384
#define DIMO  2048
#define KNN   10
#define KSEL  16
#define FINF  3.0e38f
#define BK    64
#define PITCH 72   // bf16 elems per LDS row: 64 data + 8 pad (144B = 36 words -> balanced banks)

typedef __attribute__((ext_vector_type(8))) short short8v;
typedef __attribute__((ext_vector_type(4))) float float4v;

__device__ __forceinline__ unsigned short f2bf(float x) {
    union { float f; unsigned u; } c; c.f = x;
    unsigned lsb = (c.u >> 16) & 1u;                 // round-to-nearest-even
    return (unsigned short)((c.u + 0x7FFFu + lsb) >> 16);
}

// -------------------------------------------------------------------------
// Kernel 1: bf16-MFMA approx score + per-block per-row top-10 candidates.
// approx_score[m][n] = ||d_n||^2 (exact f32) - 2 * bf16dot(t_m, d_n)
// (error ~0.16 absolute vs multi-unit top-k margins -> candidate-safe).
// Tile: 128 targets x 128 data cols, BK=64, 4 waves in 2x2, each wave a
// 64x64 sub-tile of 4x4 16x16x32-bf16 fragments.
// -------------------------------------------------------------------------
__global__ __launch_bounds__(256) void score_topk_kernel(
    const float* __restrict__ tgt,     // [128][384]
    const float* __restrict__ dat,     // [N][384]
    float* __restrict__ cand_s,        // [128][nblk*10]
    int*   __restrict__ cand_i,        // [128][nblk*10]
    int N, int nblk)
{
    __shared__ unsigned short tAB[2 * 128 * PITCH];           // 36 KB
    unsigned short* tA = tAB;
    unsigned short* tB = tAB + 128 * PITCH;
    float (*sc)[129] = reinterpret_cast<float(*)[129]>(tAB);  // 33 KB overlay (epilogue)
    __shared__ float d2p[128][8];
    __shared__ float d2s[128];

    const int tid   = threadIdx.x;
    const int nbase = blockIdx.x * 128;
    const int lane  = tid & 63;
    const int wv    = tid >> 6;
    const int wr    = wv >> 1;         // wave row 0..1 (rows wr*64..+63)
    const int wc    = wv & 1;          // wave col 0..1 (cols wc*64..+63)
    const int r0    = tid >> 3;        // staging row base 0..31
    const int c8    = tid & 7;         // staging col-group (8 floats)

    const int frow  = lane & 15;       // A row / B col within fragment
    const int kg    = lane >> 4;       // k-group 0..3 (8 bf16 each)

    float4v acc[4][4];
#pragma unroll
    for (int i = 0; i < 4; ++i)
#pragma unroll
        for (int j = 0; j < 4; ++j) acc[i][j] = (float4v){0.f, 0.f, 0.f, 0.f};

    float d2acc[4] = {0.f, 0.f, 0.f, 0.f};

    for (int k0 = 0; k0 < DIM; k0 += BK) {
        __syncthreads();
        // stage targets tile -> bf16 LDS [row][k] (pitch 72)
#pragma unroll
        for (int it = 0; it < 4; ++it) {
            int row = it * 32 + r0;
            const float* s = &tgt[row * DIM + k0 + c8 * 8];
            float4 u0 = *reinterpret_cast<const float4*>(s);
            float4 u1 = *reinterpret_cast<const float4*>(s + 4);
            short8v h;
            h[0] = (short)f2bf(u0.x); h[1] = (short)f2bf(u0.y);
            h[2] = (short)f2bf(u0.z); h[3] = (short)f2bf(u0.w);
            h[4] = (short)f2bf(u1.x); h[5] = (short)f2bf(u1.y);
            h[6] = (short)f2bf(u1.z); h[7] = (short)f2bf(u1.w);
            *reinterpret_cast<short8v*>(&tA[row * PITCH + c8 * 8]) = h;
        }
        // stage data tile -> bf16 LDS + exact-f32 ||d||^2 partials
#pragma unroll
        for (int it = 0; it < 4; ++it) {
            int row = it * 32 + r0;
            int g   = nbase + row;
            float4 u0 = make_float4(0.f, 0.f, 0.f, 0.f);
            float4 u1 = make_float4(0.f, 0.f, 0.f, 0.f);
            if (g < N) {
                const float* s = &dat[(size_t)g * DIM + k0 + c8 * 8];
                u0 = *reinterpret_cast<const float4*>(s);
                u1 = *reinterpret_cast<const float4*>(s + 4);
            }
            d2acc[it] += u0.x * u0.x + u0.y * u0.y + u0.z * u0.z + u0.w * u0.w
                       + u1.x * u1.x + u1.y * u1.y + u1.z * u1.z + u1.w * u1.w;
            short8v h;
            h[0] = (short)f2bf(u0.x); h[1] = (short)f2bf(u0.y);
            h[2] = (short)f2bf(u0.z); h[3] = (short)f2bf(u0.w);
            h[4] = (short)f2bf(u1.x); h[5] = (short)f2bf(u1.y);
            h[6] = (short)f2bf(u1.z); h[7] = (short)f2bf(u1.w);
            *reinterpret_cast<short8v*>(&tB[row * PITCH + c8 * 8]) = h;
        }
        __syncthreads();
        // MFMA: 2 k-steps of 32, 4x4 fragments per wave
#pragma unroll
        for (int ks = 0; ks < 2; ++ks) {
            short8v a[4], b[4];
            const int koff = ks * 32 + kg * 8;
#pragma unroll
            for (int f = 0; f < 4; ++f) {
                a[f] = *reinterpret_cast<const short8v*>(
                    &tA[(wr * 64 + f * 16 + frow) * PITCH + koff]);
                b[f] = *reinterpret_cast<const short8v*>(
                    &tB[(wc * 64 + f * 16 + frow) * PITCH + koff]);
            }
#pragma unroll
            for (int fr = 0; fr < 4; ++fr)
#pragma unroll
                for (int fc = 0; fc < 4; ++fc)
                    acc[fr][fc] = __builtin_amdgcn_mfma_f32_16x16x32_bf16(
                        a[fr], b[fc], acc[fr][fc], 0, 0, 0);
        }
    }

    // reduce ||d||^2 partials (exact f32, approx path only)
    __syncthreads();
#pragma unroll
    for (int it = 0; it < 4; ++it) d2p[it * 32 + r0][c8] = d2acc[it];
    __syncthreads();
    if (tid < 128) {
        float s = 0.f;
#pragma unroll
        for (int j = 0; j < 8; ++j) s += d2p[tid][j];
        d2s[tid] = s;
    }

    // epilogue: two 64-row halves; C/D layout: col=lane&15, row=kg*4+reg
    const int M = nblk * KNN;
    for (int h = 0; h < 2; ++h) {
        __syncthreads();
        if (wr == h) {
#pragma unroll
            for (int fr = 0; fr < 4; ++fr)
#pragma unroll
                for (int fc = 0; fc < 4; ++fc)
#pragma unroll
                    for (int e = 0; e < 4; ++e) {
                        int lr = fr * 16 + kg * 4 + e;          // local row 0..63
                        int lc = wc * 64 + fc * 16 + frow;      // local col 0..127
                        int n  = nbase + lc;
                        sc[lr][lc] = (n < N) ? d2s[lc] - 2.f * acc[fr][fc][e]
                                             : FINF;
                    }
        }
        __syncthreads();
        if (tid < 64) {
            int grow = h * 64 + tid;
            float ts[KNN];
            int   ti[KNN];
#pragma unroll
            for (int k = 0; k < KNN; ++k) { ts[k] = FINF; ti[k] = 0x7fffffff; }
            for (int c = 0; c < 128; ++c) {
                float s = sc[tid][c];
                if (s < ts[KNN - 1]) {
                    ts[KNN - 1] = s;
                    ti[KNN - 1] = nbase + c;
#pragma unroll
                    for (int p = KNN - 1; p > 0; --p) {
                        if (ts[p] < ts[p - 1]) {
                            float fs = ts[p]; ts[p] = ts[p - 1]; ts[p - 1] = fs;
                            int   fi = ti[p]; ti[p] = ti[p - 1]; ti[p - 1] = fi;
                        }
                    }
                }
            }
            size_t base = (size_t)grow * M + (size_t)blockIdx.x * KNN;
#pragma unroll
            for (int k = 0; k < KNN; ++k) {
                cand_s[base + k] = ts[k];
                cand_i[base + k] = ti[k];
            }
        }
    }
}

// -------------------------------------------------------------------------
// Kernel 2: merge per-block candidates -> approx top-16, exact-f32 rescore
// (bit-replicating the round-1 arithmetic that matched np), select top-10.
// -------------------------------------------------------------------------
__global__ __launch_bounds__(256) void select_rescore_kernel(
    const float* __restrict__ cand_s,  // [B][M]
    const int*   __restrict__ cand_i,  // [B][M]
    const float* __restrict__ tgt,     // [128][384]
    const float* __restrict__ dat,     // [N][384]
    int* __restrict__ seldev,          // [B][10]
    int M)
{
    const int b   = blockIdx.x;
    const int tid = threadIdx.x;
    const float* rs_ = cand_s + (size_t)b * M;
    const int*   ri_ = cand_i + (size_t)b * M;

    // per-thread approx top-16 (lex (score, idx)) — static indexing only
    float ts[KSEL];
    int   ti[KSEL];
#pragma unroll
    for (int k = 0; k < KSEL; ++k) { ts[k] = FINF; ti[k] = 0x7fffffff; }

    for (int j = tid; j < M; j += 256) {
        float s  = rs_[j];
        int   id = ri_[j];
        if (s < ts[KSEL - 1] || (s == ts[KSEL - 1] && id < ti[KSEL - 1])) {
            ts[KSEL - 1] = s;
            ti[KSEL - 1] = id;
#pragma unroll
            for (int p = KSEL - 1; p > 0; --p) {
                bool sw = (ts[p] < ts[p - 1]) ||
                          (ts[p] == ts[p - 1] && ti[p] < ti[p - 1]);
                if (sw) {
                    float fs = ts[p]; ts[p] = ts[p - 1]; ts[p - 1] = fs;
                    int   fi = ti[p]; ti[p] = ti[p - 1]; ti[p - 1] = fi;
                }
            }
        }
    }

    __shared__ float cs[256 * KSEL];
    __shared__ int   ci[256 * KSEL];
    __shared__ float rs[256];
    __shared__ int   ri[256];
    __shared__ int   rt[256];
    __shared__ int   sel16[KSEL];
    __shared__ float ex_s[KSEL];
    __shared__ int   ex_i[KSEL];

#pragma unroll
    for (int k = 0; k < KSEL; ++k) {
        cs[tid * KSEL + k] = ts[k];
        ci[tid * KSEL + k] = ti[k];
    }

    int ptr = 0;
    for (int k = 0; k < KSEL; ++k) {
        rs[tid] = cs[tid * KSEL + ptr];
        ri[tid] = ci[tid * KSEL + ptr];
        rt[tid] = tid;
        __syncthreads();
        for (int off = 128; off > 0; off >>= 1) {
            if (tid < off) {
                float s2 = rs[tid + off]; int i2 = ri[tid + off];
                float s1 = rs[tid];       int i1 = ri[tid];
                if (s2 < s1 || (s2 == s1 && i2 < i1)) {
                    rs[tid] = s2; ri[tid] = i2; rt[tid] = rt[tid + off];
                }
            }
            __syncthreads();
        }
        if (tid == 0) sel16[k] = ri[0];
        if (tid == rt[0]) ptr++;
        __syncthreads();
    }

    // exact f32 rescore — replicates round-1 kernel arithmetic exactly:
    // d2 partials grouped by 4-float column-group over k-chunks of 32,
    // dot = sequential fmaf chain k=0..383, score = d2 - 2.f*dot.
    if (tid < KSEL) {
        const int n = sel16[tid];
        float d2p_[8] = {0.f, 0.f, 0.f, 0.f, 0.f, 0.f, 0.f, 0.f};
        float dot = 0.f;
        for (int c = 0; c < DIM / 32; ++c) {
#pragma unroll
            for (int j = 0; j < 8; ++j) {
                const float4 v = *reinterpret_cast<const float4*>(
                    &dat[(size_t)n * DIM + c * 32 + j * 4]);
                const float4 t = *reinterpret_cast<const float4*>(
                    &tgt[(size_t)b * DIM + c * 32 + j * 4]);
                d2p_[j] += v.x * v.x + v.y * v.y + v.z * v.z + v.w * v.w;
                dot = fmaf(t.x, v.x, dot);
                dot = fmaf(t.y, v.y, dot);
                dot = fmaf(t.z, v.z, dot);
                dot = fmaf(t.w, v.w, dot);
            }
        }
        float d2 = 0.f;
#pragma unroll
        for (int j = 0; j < 8; ++j) d2 += d2p_[j];
        ex_s[tid] = d2 - 2.f * dot;
        ex_i[tid] = n;
    }
    __syncthreads();

    if (tid == 0) {
        float fs[KNN]; int fi[KNN];
#pragma unroll
        for (int k = 0; k < KNN; ++k) { fs[k] = FINF; fi[k] = 0x7fffffff; }
        for (int q = 0; q < KSEL; ++q) {
            float s  = ex_s[q];
            int   id = ex_i[q];
            if (s < fs[KNN - 1] || (s == fs[KNN - 1] && id < fi[KNN - 1])) {
                fs[KNN - 1] = s;
                fi[KNN - 1] = id;
#pragma unroll
                for (int p = KNN - 1; p > 0; --p) {
                    bool sw = (fs[p] < fs[p - 1]) ||
                              (fs[p] == fs[p - 1] && fi[p] < fi[p - 1]);
                    if (sw) {
                        float a = fs[p]; fs[p] = fs[p - 1]; fs[p - 1] = a;
                        int   i2 = fi[p]; fi[p] = fi[p - 1]; fi[p - 1] = i2;
                    }
                }
            }
        }
#pragma unroll
        for (int k = 0; k < KNN; ++k) seldev[b * KNN + k] = fi[k];
    }
}

// -------------------------------------------------------------------------
// Kernel 3: gather. One block per (target, k) pair.
// -------------------------------------------------------------------------
__global__ __launch_bounds__(256) void gather_kernel(
    const int* __restrict__ seldev,    // [B*10]
    const float* __restrict__ OTin,    // [N][384]
    const float* __restrict__ OTout,   // [N][2048]
    float* __restrict__ out,           // [B*10*384] ++ [B*10*2048]
    int B)
{
    const int bid = blockIdx.x;
    const int tid = threadIdx.x;
    const int idx = seldev[bid];
    const size_t o1 = (size_t)B * KNN * DIM;

    const float4* in4  = reinterpret_cast<const float4*>(&OTin[(size_t)idx * DIM]);
    float4*       out4 = reinterpret_cast<float4*>(&out[(size_t)bid * DIM]);
    for (int q = tid; q < DIM / 4; q += 256) out4[q] = in4[q];

    const float4* ino4  = reinterpret_cast<const float4*>(&OTout[(size_t)idx * DIMO]);
    float4*       outo4 = reinterpret_cast<float4*>(&out[o1 + (size_t)bid * DIMO]);
    for (int q = tid; q < DIMO / 4; q += 256) outo4[q] = ino4[q];
}

extern "C" void kernel_launch(void* const* d_in, const int* in_sizes, int n_in,
                              void* d_out, int out_size, void* d_ws, size_t ws_size,
                              hipStream_t stream) {
    const float* targets = (const float*)d_in[0];
    const float* data    = (const float*)d_in[1];
    const float* OTin    = (const float*)d_in[2];
    const float* OTout   = (const float*)d_in[3];
    float* out = (float*)d_out;

    const int B = in_sizes[0] / DIM;   // 128
    const int N = in_sizes[1] / DIM;   // 50000

    const int nblk = (N + 127) / 128;  // 391
    const int M    = nblk * KNN;       // 3910

    float* cand_s = (float*)d_ws;                       // B*M floats
    int*   cand_i = (int*)(cand_s + (size_t)B * M);     // B*M ints
    int*   seldev = (int*)(cand_i + (size_t)B * M);     // B*KNN ints

    score_topk_kernel<<<nblk, 256, 0, stream>>>(targets, data, cand_s, cand_i, N, nblk);
    select_rescore_kernel<<<B, 256, 0, stream>>>(cand_s, cand_i, targets, data, seldev, M);
    gather_kernel<<<B * KNN, 256, 0, stream>>>(seldev, OTin, OTout, out, B);
}